// Round 10
// baseline (261.997 us; speedup 1.0000x reference)
//
#include <hip/hip_runtime.h>
#include <stdint.h>

// ---- problem constants ----
constexpr int Mdim = 8192;
constexpr int Ndim = 4096;
constexpr int Kdim = 4096;
constexpr int NT = Kdim / 128;  // 32 K-tiles of BK=128

#define ISF        ((float)(2.0 / 255.0))          // IN_SCALE
#define OUT_SCALE  ((float)(2.0 / 255.0 * 0.01))   // IN_SCALE * W_SCALE
#define BSCALE     0.01f
// IN_ZP = 127 (the +1e-12 pulls 127.5 below the .5 boundary). x_shifted in [-127,128]
// doesn't fit int8 -> compute u = x_q - 128 in [-128,127]; acc = GEMM(u,w) + rowsum_w[n].

typedef int i32x4 __attribute__((ext_vector_type(4)));

// ---------------- pre-pass 1: quantize x_float -> int8
__global__ __launch_bounds__(256) void quantize_x(const float* __restrict__ x,
                                                  int* __restrict__ x8,
                                                  int ngroups) {
  int idx = blockIdx.x * 256 + threadIdx.x;
  int stride = gridDim.x * 256;
  for (int g = idx; g < ngroups; g += stride) {
    float4 v = reinterpret_cast<const float4*>(x)[g];
    int a0 = (int)rintf(v.x / ISF + 127.0f);
    int a1 = (int)rintf(v.y / ISF + 127.0f);
    int a2 = (int)rintf(v.z / ISF + 127.0f);
    int a3 = (int)rintf(v.w / ISF + 127.0f);
    a0 = a0 < 0 ? 0 : (a0 > 255 ? 255 : a0); a0 -= 128;
    a1 = a1 < 0 ? 0 : (a1 > 255 ? 255 : a1); a1 -= 128;
    a2 = a2 < 0 ? 0 : (a2 > 255 ? 255 : a2); a2 -= 128;
    a3 = a3 < 0 ? 0 : (a3 > 255 ? 255 : a3); a3 -= 128;
    x8[g] = (a0 & 0xff) | ((a1 & 0xff) << 8) | ((a2 & 0xff) << 16) |
            (int)(((unsigned)(a3 & 0xff)) << 24);
  }
}

// ---------------- pre-pass 2: w_q int32 -> int8 packed, fused per-row sum
__global__ __launch_bounds__(256) void convert_w(const int* __restrict__ wq,
                                                 int* __restrict__ w8,
                                                 int* __restrict__ wsum) {
  int row = blockIdx.x;
  const int4* src = reinterpret_cast<const int4*>(wq + (size_t)row * Kdim);
  int* dst = w8 + (size_t)row * (Kdim / 4);
  int s = 0;
#pragma unroll
  for (int i = 0; i < 4; ++i) {
    int idx = i * 256 + threadIdx.x;
    int4 v = src[idx];
    s += v.x + v.y + v.z + v.w;
    dst[idx] = (v.x & 0xff) | ((v.y & 0xff) << 8) | ((v.z & 0xff) << 16) |
               (int)(((unsigned)(v.w & 0xff)) << 24);
  }
  __shared__ int red[256];
  red[threadIdx.x] = s;
  __syncthreads();
  for (int off = 128; off; off >>= 1) {
    if ((int)threadIdx.x < off) red[threadIdx.x] += red[threadIdx.x + off];
    __syncthreads();
  }
  if (threadIdx.x == 0) wsum[row] = red[0];
}

// ---------------- 256x256, BK=128, 8 waves. ONE barrier per K-tile; NO intra-tile
// fences: the tile body is a flat 24-ds_read + 64-MFMA region and the COMPILER
// schedules it (it natively emits counted lgkmcnt per consumer — m97 evidence).
// A triple-buffered, B double. Counted vmcnt(4).
// LDS: A 3x32768 @0; B 2x32768 @98304 = 163840 B.
#define AS1C const __attribute__((address_space(1))) void*
#define AS3  __attribute__((address_space(3))) void*
#define GLL(src, dst) __builtin_amdgcn_global_load_lds((AS1C)(src), (AS3)(dst), 16, 0, 0)
#define BAR() asm volatile("s_barrier" ::: "memory")
#define VMC(N) asm volatile("s_waitcnt vmcnt(" #N ")" ::: "memory")
#define MFMA(a, b, c) __builtin_amdgcn_mfma_i32_16x16x64_i8(a, b, c, 0, 0, 0)
#define BBASE 98304

__global__ __launch_bounds__(512, 2) void gemm_i8_free(const int8_t* __restrict__ A8,
                                                       const int8_t* __restrict__ B8,
                                                       const int* __restrict__ wsum,
                                                       const int* __restrict__ bq,
                                                       float* __restrict__ out) {
  __shared__ uint8_t lds[163840];

  // bijective XCD swizzle: 512 blocks, 512 % 8 == 0
  int bid = blockIdx.x;
  int wg = (bid & 7) * 64 + (bid >> 3);
  int bm = wg >> 4;  // 32 row-tiles
  int bn = wg & 15;  // 16 col-tiles

  const int tid = threadIdx.x;
  const int lane = tid & 63;
  const int wv = tid >> 6;   // 0..7
  const int wr = wv >> 2;    // 0..1 : 128-row half of C
  const int wc = wv & 3;     // 0..3 : 64-col quarter of C
  const int l15 = lane & 15, hi = lane >> 4;

  // staging source (per lane): row-chunk r3, slot s3, pre-swizzled col (rule #21)
  const int r3 = lane >> 3, s3 = lane & 7;
  const int swcol = (s3 ^ r3) << 4;
  const size_t aoff = (size_t)(bm * 256 + wv * 8 + r3) * Kdim + swcol;
  const size_t boff = (size_t)(bn * 256 + wv * 8 + r3) * Kdim + swcol;
  const int ldsw = wv * 1024;

#define ISSUE_A(P, t, half) do { \
    GLL(A8 + aoff + (size_t)(t) * 128 + (size_t)((half) * 128) * Kdim, \
        &lds[(P) * 32768 + (half) * 16384 + ldsw]); \
    GLL(A8 + aoff + (size_t)(t) * 128 + (size_t)((half) * 128 + 64) * Kdim, \
        &lds[(P) * 32768 + (half) * 16384 + 8192 + ldsw]); \
  } while (0)
#define ISSUE_B(P, t, half) do { \
    GLL(B8 + boff + (size_t)(t) * 128 + (size_t)((half) * 128) * Kdim, \
        &lds[BBASE + (P) * 32768 + (half) * 16384 + ldsw]); \
    GLL(B8 + boff + (size_t)(t) * 128 + (size_t)((half) * 128 + 64) * Kdim, \
        &lds[BBASE + (P) * 32768 + (half) * 16384 + 8192 + ldsw]); \
  } while (0)

  // fragment addressing (round-2 verified, 0 conflicts): slot = (ks*4+hi) ^ (l15&7)
  const int aRow = (wr * 128 + l15) * 128;
  const int bRow = (wc * 64 + l15) * 128;
  const int sl0 = (hi ^ (l15 & 7)) << 4;
  const int sl1 = ((4 + hi) ^ (l15 & 7)) << 4;

#define LDA(P, i, ks) (*reinterpret_cast<const i32x4*>( \
    &lds[(P) * 32768 + aRow + (i) * 2048 + ((ks) ? sl1 : sl0)]))
#define LDB(P, j, ks) (*reinterpret_cast<const i32x4*>( \
    &lds[BBASE + (P) * 32768 + bRow + (j) * 2048 + ((ks) ? sl1 : sl0)]))

  i32x4 acc[8][4];
#pragma unroll
  for (int i = 0; i < 8; ++i)
#pragma unroll
    for (int j = 0; j < 4; ++j) acc[i][j] = (i32x4){0, 0, 0, 0};

  // prologue: A(0),B(0) (8 GLL) + A(1) (4 GLL); vmcnt(4) retires A0+B0.
  ISSUE_A(0, 0, 0); ISSUE_A(0, 0, 1);
  ISSUE_B(0, 0, 0); ISSUE_B(0, 0, 1);
  ISSUE_A(1, 1, 0); ISSUE_A(1, 1, 1);
  VMC(4);
  BAR();

  // Tile t: A buf TA=t%3, B buf TB=t&1. GLLs at top: B(t+1)->TB^1 and A(t+2)->TA2
  // (both buffers' last reads were in tile t-1, retired before t-1's closing BAR
  // by the compiler's lgkm waits in front of their consumer MFMAs). Body: flat
  // 24-read + 64-MFMA region, compiler-scheduled (reads interleave into the MFMA
  // stream with counted lgkm waits). vmcnt(4) at end retires A(t+1)+B(t+1) (8
  // oldest of 12 in flight), leaves A(t+2) — never drains to 0 in steady state.
#define TILE(TA, TB, TA2, t, DOB, DOA, VM4, VM0) do { \
    if (DOB) { ISSUE_B((TB) ^ 1, (t) + 1, 0); ISSUE_B((TB) ^ 1, (t) + 1, 1); } \
    if (DOA) { ISSUE_A(TA2, (t) + 2, 0); ISSUE_A(TA2, (t) + 2, 1); } \
    i32x4 a0[8], B0[4], a1[8], B1[4]; \
    B0[0] = LDB(TB, 0, 0); B0[1] = LDB(TB, 1, 0); B0[2] = LDB(TB, 2, 0); B0[3] = LDB(TB, 3, 0); \
    _Pragma("unroll") for (int i = 0; i < 8; ++i) a0[i] = LDA(TA, i, 0); \
    _Pragma("unroll") for (int i = 0; i < 8; ++i) \
      _Pragma("unroll") for (int j = 0; j < 4; ++j) \
        acc[i][j] = MFMA(a0[i], B0[j], acc[i][j]); \
    B1[0] = LDB(TB, 0, 1); B1[1] = LDB(TB, 1, 1); B1[2] = LDB(TB, 2, 1); B1[3] = LDB(TB, 3, 1); \
    _Pragma("unroll") for (int i = 0; i < 8; ++i) a1[i] = LDA(TA, i, 1); \
    _Pragma("unroll") for (int i = 0; i < 8; ++i) \
      _Pragma("unroll") for (int j = 0; j < 4; ++j) \
        acc[i][j] = MFMA(a1[i], B1[j], acc[i][j]); \
    if (VM4) VMC(4); \
    if (VM0) VMC(0); \
    BAR(); \
  } while (0)

  for (int it = 0; it < 5; ++it) {  // 30 tiles: t = 0..29
    int t = it * 6;
    TILE(0, 0, 2, t + 0, 1, 1, 1, 0);
    TILE(1, 1, 0, t + 1, 1, 1, 1, 0);
    TILE(2, 0, 1, t + 2, 1, 1, 1, 0);
    TILE(0, 1, 2, t + 3, 1, 1, 1, 0);
    TILE(1, 0, 0, t + 4, 1, 1, 1, 0);
    TILE(2, 1, 1, t + 5, 1, 1, 1, 0);
  }
  // t=30 (TA=0,TB=0): stage B(31) only; drain all before tile31. t=31 (TA=1,TB=1).
  TILE(0, 0, 2, 30, 1, 0, 0, 1);
  TILE(1, 1, 0, 31, 0, 0, 0, 0);

  // epilogue: C/D layout col = lane&15, row = (lane>>4)*4 + reg
#pragma unroll
  for (int j = 0; j < 4; ++j) {
    int col = bn * 256 + wc * 64 + j * 16 + l15;
    float fb = (float)bq[col] * BSCALE;
    int ws = wsum[col];
#pragma unroll
    for (int i = 0; i < 8; ++i) {
      int rbase = bm * 256 + wr * 128 + i * 16 + hi * 4;
#pragma unroll
      for (int p = 0; p < 4; ++p)
        out[(size_t)(rbase + p) * Ndim + col] = (float)(acc[i][j][p] + ws) * OUT_SCALE + fb;
    }
  }
#undef TILE
#undef ISSUE_A
#undef ISSUE_B
#undef LDA
#undef LDB
}

// ---------------- naive fallback (only if ws_size is unexpectedly small)
__global__ void fallback_kernel(const float* __restrict__ x, const int* __restrict__ wq,
                                const int* __restrict__ bq, float* __restrict__ out) {
  int col = blockIdx.x * 16 + (threadIdx.x & 15);
  int row = blockIdx.y * 16 + (threadIdx.x >> 4);
  const float* xr = x + (size_t)row * Kdim;
  const int* wr_ = wq + (size_t)col * Kdim;
  int acc = 0;
  for (int k = 0; k < Kdim; ++k) {
    int v = (int)rintf(xr[k] / ISF + 127.0f);
    v = v < 0 ? 0 : (v > 255 ? 255 : v);
    acc += (v - 127) * wr_[k];
  }
  out[(size_t)row * Ndim + col] = (float)acc * OUT_SCALE + (float)bq[col] * BSCALE;
}

extern "C" void kernel_launch(void* const* d_in, const int* in_sizes, int n_in,
                              void* d_out, int out_size, void* d_ws, size_t ws_size,
                              hipStream_t stream) {
  const float* x = (const float*)d_in[0];
  const int* wq = (const int*)d_in[1];
  const int* bq = (const int*)d_in[2];
  float* out = (float*)d_out;

  const size_t x8_bytes = (size_t)Mdim * Kdim;  // 32 MiB
  const size_t w8_bytes = (size_t)Ndim * Kdim;  // 16 MiB
  const size_t ws_need = x8_bytes + w8_bytes + (size_t)Ndim * sizeof(int);

  if (ws_size >= ws_need) {
    int8_t* x8 = (int8_t*)d_ws;
    int8_t* w8 = x8 + x8_bytes;
    int* wsum = (int*)(w8 + w8_bytes);

    quantize_x<<<2048, 256, 0, stream>>>(x, (int*)x8, Mdim * Kdim / 4);
    convert_w<<<Ndim, 256, 0, stream>>>(wq, (int*)w8, wsum);
    gemm_i8_free<<<(Mdim / 256) * (Ndim / 256), 512, 0, stream>>>(x8, w8, wsum, bq, out);
  } else {
    dim3 grid(Ndim / 16, Mdim / 16);
    fallback_kernel<<<grid, 256, 0, stream>>>(x, wq, bq, out);
  }
}